// Round 1
// baseline (1920.957 us; speedup 1.0000x reference)
//
#include <hip/hip_runtime.h>
#include <math.h>

// Problem constants (fixed by the reference setup)
constexpr int Nn = 131072;   // rows
constexpr int Dd = 256;      // feature dim
constexpr int Pp = 64;       // proj dim
constexpr int Gg = 8192;     // groups
constexpr int Ee = 260096;   // edges
constexpr float SIM_TH = 0.5f;

// ---------------------------------------------------------------------------
// K1: fused projection + group scatter-add.
// lane = row: each lane owns one feature row and all 64 output columns.
// W accesses are wave-uniform -> scalar (s_load) path, leaving VALU for FMAs.
// Features are read from HBM exactly once (proj FMAs + scatter atomics share
// the same float4 load).
// block = 256 threads (4 waves), 64 rows/lane-wave -> 256 rows/block.
// ---------------------------------------------------------------------------
__global__ __launch_bounds__(256) void k_proj_scatter(
    const float* __restrict__ features,   // [N][D]
    const float* __restrict__ W,          // [D][P]
    const int*   __restrict__ gid,        // [N]
    float* __restrict__ proj,             // [N][P]  (workspace)
    float* __restrict__ gsum,             // [G][D]  (head of d_out, pre-zeroed)
    float* __restrict__ gcnt)             // [G]     (workspace, pre-zeroed)
{
    const int lane = threadIdx.x & 63;
    const int wave = threadIdx.x >> 6;
    const int row  = (blockIdx.x * 4 + wave) * 64 + lane;

    float acc[Pp];
#pragma unroll
    for (int c = 0; c < Pp; ++c) acc[c] = 0.0f;

    const float* __restrict__ frow = features + (size_t)row * Dd;
    const int g = gid[row];
    float* gs = gsum + (size_t)g * Dd;
    atomicAdd(&gcnt[g], 1.0f);

    for (int d = 0; d < Dd; d += 4) {
        const float4 f = *reinterpret_cast<const float4*>(frow + d);
        // scatter-add this row chunk into its group sum (fire-and-forget)
        atomicAdd(&gs[d + 0], f.x);
        atomicAdd(&gs[d + 1], f.y);
        atomicAdd(&gs[d + 2], f.z);
        atomicAdd(&gs[d + 3], f.w);
        const float* __restrict__ w0 = W + (size_t)d * Pp;  // wave-uniform
#pragma unroll
        for (int c = 0; c < Pp; ++c) acc[c] = fmaf(f.x, w0[c],          acc[c]);
#pragma unroll
        for (int c = 0; c < Pp; ++c) acc[c] = fmaf(f.y, w0[Pp + c],     acc[c]);
#pragma unroll
        for (int c = 0; c < Pp; ++c) acc[c] = fmaf(f.z, w0[2 * Pp + c], acc[c]);
#pragma unroll
        for (int c = 0; c < Pp; ++c) acc[c] = fmaf(f.w, w0[3 * Pp + c], acc[c]);
    }

    // write proj row (row-major [N][P] so the edge kernel's gathers coalesce)
    float4* prow = reinterpret_cast<float4*>(proj + (size_t)row * Pp);
#pragma unroll
    for (int c = 0; c < Pp; c += 4) {
        prow[c >> 2] = make_float4(acc[c], acc[c + 1], acc[c + 2], acc[c + 3]);
    }
}

// ---------------------------------------------------------------------------
// K2: divide group sums by counts, in place in d_out. One float4 per thread.
// ---------------------------------------------------------------------------
__global__ __launch_bounds__(256) void k_finalize(
    float* __restrict__ out,              // [G*D] sums -> means
    const float* __restrict__ gcnt)       // [G]
{
    const int i = blockIdx.x * 256 + threadIdx.x;   // float4 index, < G*D/4
    const int g = i >> 6;                            // 64 float4 per group row
    const float inv = 1.0f / fmaxf(gcnt[g], 1.0f);
    float4 v = reinterpret_cast<float4*>(out)[i];
    v.x *= inv; v.y *= inv; v.z *= inv; v.w *= inv;
    reinterpret_cast<float4*>(out)[i] = v;
}

// ---------------------------------------------------------------------------
// K3: one wave per edge. lane = proj column. Coalesced 256 B row gathers
// (proj is 33.5 MB -> L3-resident), butterfly shuffle reduce, sigmoid.
// ---------------------------------------------------------------------------
__global__ __launch_bounds__(256) void k_edges(
    const float* __restrict__ proj,       // [N][P]
    const int*   __restrict__ ei,         // [2][E]
    float* __restrict__ out_logits)       // [E]
{
    const int lane = threadIdx.x & 63;
    const int e = blockIdx.x * 4 + (threadIdx.x >> 6);  // wave-uniform
    const int s = ei[e];
    const int t = ei[Ee + e];
    float v = proj[(size_t)s * Pp + lane] * proj[(size_t)t * Pp + lane];
#pragma unroll
    for (int off = 32; off >= 1; off >>= 1)
        v += __shfl_xor(v, off, 64);
    if (lane == 0)
        out_logits[e] = 1.0f / (1.0f + __expf(-(v - SIM_TH)));
}

// ---------------------------------------------------------------------------
extern "C" void kernel_launch(void* const* d_in, const int* in_sizes, int n_in,
                              void* d_out, int out_size, void* d_ws, size_t ws_size,
                              hipStream_t stream)
{
    const float* features = (const float*)d_in[0];
    const float* W        = (const float*)d_in[1];
    const int*   ei       = (const int*)d_in[2];
    const int*   gid      = (const int*)d_in[3];
    // d_in[4] = num_groups scalar (fixed at 8192, hardcoded)

    float* out  = (float*)d_out;                 // [G*D] means ++ [E] logits
    float* proj = (float*)d_ws;                  // N*P floats = 32 MB
    float* gcnt = proj + (size_t)Nn * Pp;        // G floats

    // d_out / d_ws are poisoned before every timed call -> zero accumulators.
    hipMemsetAsync(out,  0, (size_t)Gg * Dd * sizeof(float), stream);
    hipMemsetAsync(gcnt, 0, (size_t)Gg * sizeof(float), stream);

    hipLaunchKernelGGL(k_proj_scatter, dim3(Nn / 256), dim3(256), 0, stream,
                       features, W, gid, proj, out, gcnt);
    hipLaunchKernelGGL(k_finalize, dim3((Gg * Dd / 4) / 256), dim3(256), 0, stream,
                       out, gcnt);
    hipLaunchKernelGGL(k_edges, dim3(Ee / 4), dim3(256), 0, stream,
                       proj, ei, out + (size_t)Gg * Dd);
}

// Round 2
// 425.977 us; speedup vs baseline: 4.5095x; 4.5095x over previous
//
#include <hip/hip_runtime.h>
#include <math.h>

// Problem constants (fixed by the reference setup)
constexpr int Nn = 131072;   // rows
constexpr int Dd = 256;      // feature dim
constexpr int Pp = 64;       // proj dim
constexpr int Gg = 8192;     // groups
constexpr int Ee = 260096;   // edges
constexpr float SIM_TH = 0.5f;

// ---------------------------------------------------------------------------
// K1: projection (lane = row) + per-group member count.
// Each lane owns one feature row and all 64 output columns; W addresses are
// wave-uniform -> scalar-load path, VALU does only the FMAs.
// ---------------------------------------------------------------------------
__global__ __launch_bounds__(256) void k_proj_count(
    const float* __restrict__ features,   // [N][D]
    const float* __restrict__ W,          // [D][P]
    const int*   __restrict__ gid,        // [N]
    float* __restrict__ proj,             // [N][P]  (ws)
    int*   __restrict__ cnt)              // [G]     (ws, pre-zeroed)
{
    const int lane = threadIdx.x & 63;
    const int wave = threadIdx.x >> 6;
    const int row  = (blockIdx.x * 4 + wave) * 64 + lane;

    atomicAdd(&cnt[gid[row]], 1);   // 131K atomics total — trivial

    float acc[Pp];
#pragma unroll
    for (int c = 0; c < Pp; ++c) acc[c] = 0.0f;

    const float* __restrict__ frow = features + (size_t)row * Dd;
    for (int d = 0; d < Dd; d += 4) {
        const float4 f = *reinterpret_cast<const float4*>(frow + d);
        const float* __restrict__ w0 = W + (size_t)d * Pp;  // wave-uniform
#pragma unroll
        for (int c = 0; c < Pp; ++c) acc[c] = fmaf(f.x, w0[c],          acc[c]);
#pragma unroll
        for (int c = 0; c < Pp; ++c) acc[c] = fmaf(f.y, w0[Pp + c],     acc[c]);
#pragma unroll
        for (int c = 0; c < Pp; ++c) acc[c] = fmaf(f.z, w0[2 * Pp + c], acc[c]);
#pragma unroll
        for (int c = 0; c < Pp; ++c) acc[c] = fmaf(f.w, w0[3 * Pp + c], acc[c]);
    }

    float4* prow = reinterpret_cast<float4*>(proj + (size_t)row * Pp);
#pragma unroll
    for (int c = 0; c < Pp; c += 4)
        prow[c >> 2] = make_float4(acc[c], acc[c + 1], acc[c + 2], acc[c + 3]);
}

// ---------------------------------------------------------------------------
// K2: single-block exclusive prefix scan over the 8192 group counts.
// 256 threads x 32 groups each; Hillis-Steele on the 256 per-thread sums.
// Writes bucket offsets (for the gather) and cursors (for the scatter).
// ---------------------------------------------------------------------------
__global__ __launch_bounds__(256) void k_scan(
    const int* __restrict__ cnt,          // [G]
    int* __restrict__ offsets,            // [G]
    int* __restrict__ cursor)             // [G]
{
    __shared__ int lds[256];
    const int t = threadIdx.x;
    const int base = t * 32;

    int s = 0;
#pragma unroll
    for (int j = 0; j < 32; ++j) s += cnt[base + j];
    lds[t] = s;
    __syncthreads();

    int v = s;
    for (int off = 1; off < 256; off <<= 1) {
        int add = (t >= off) ? lds[t - off] : 0;
        __syncthreads();
        v += add;
        lds[t] = v;
        __syncthreads();
    }

    int run = v - s;   // exclusive prefix of this thread's 32-group chunk
    for (int j = 0; j < 32; ++j) {
        offsets[base + j] = run;
        cursor[base + j]  = run;
        run += cnt[base + j];
    }
}

// ---------------------------------------------------------------------------
// K3: scatter row indices into group buckets (counting sort, phase 2).
// ---------------------------------------------------------------------------
__global__ __launch_bounds__(256) void k_scatter_idx(
    const int* __restrict__ gid,          // [N]
    int* __restrict__ cursor,             // [G]
    int* __restrict__ bucket)             // [N]
{
    const int i = blockIdx.x * 256 + threadIdx.x;
    const int p = atomicAdd(&cursor[gid[i]], 1);
    bucket[p] = i;
}

// ---------------------------------------------------------------------------
// K4: one block per group: gather member rows (coalesced 1 KB reads), sum in
// registers, divide by count, write mean. Zero atomics; writes d_out fully.
// ---------------------------------------------------------------------------
__global__ __launch_bounds__(256) void k_group_mean(
    const float* __restrict__ features,   // [N][D]
    const int* __restrict__ bucket,       // [N]
    const int* __restrict__ offsets,      // [G]
    const int* __restrict__ cnt,          // [G]
    float* __restrict__ out_means)        // [G][D]
{
    const int g = blockIdx.x;
    const int t = threadIdx.x;            // = column d
    const int n = cnt[g];
    const int start = offsets[g];

    float s = 0.0f;
    for (int k = 0; k < n; ++k) {
        const int r = bucket[start + k];  // wave-uniform
        s += features[(size_t)r * Dd + t];
    }
    out_means[(size_t)g * Dd + t] = s / (float)max(n, 1);
}

// ---------------------------------------------------------------------------
// K5: one wave per edge: dual 256 B row gathers, butterfly reduce, sigmoid.
// ---------------------------------------------------------------------------
__global__ __launch_bounds__(256) void k_edges(
    const float* __restrict__ proj,       // [N][P]
    const int*   __restrict__ ei,         // [2][E]
    float* __restrict__ out_logits)       // [E]
{
    const int lane = threadIdx.x & 63;
    const int e = blockIdx.x * 4 + (threadIdx.x >> 6);  // wave-uniform
    const int s = ei[e];
    const int t = ei[Ee + e];
    float v = proj[(size_t)s * Pp + lane] * proj[(size_t)t * Pp + lane];
#pragma unroll
    for (int off = 32; off >= 1; off >>= 1)
        v += __shfl_xor(v, off, 64);
    if (lane == 0)
        out_logits[e] = 1.0f / (1.0f + __expf(-(v - SIM_TH)));
}

// ---------------------------------------------------------------------------
extern "C" void kernel_launch(void* const* d_in, const int* in_sizes, int n_in,
                              void* d_out, int out_size, void* d_ws, size_t ws_size,
                              hipStream_t stream)
{
    const float* features = (const float*)d_in[0];
    const float* W        = (const float*)d_in[1];
    const int*   ei       = (const int*)d_in[2];
    const int*   gid      = (const int*)d_in[3];
    // d_in[4] = num_groups scalar (fixed at 8192, hardcoded)

    float* out_means  = (float*)d_out;                    // [G*D]
    float* out_logits = out_means + (size_t)Gg * Dd;      // [E]

    float* proj    = (float*)d_ws;                        // N*P floats (32 MB)
    int*   bucket  = (int*)(proj + (size_t)Nn * Pp);      // [N]
    int*   cnt     = bucket + Nn;                         // [G]
    int*   offsets = cnt + Gg;                            // [G]
    int*   cursor  = offsets + Gg;                        // [G]

    hipMemsetAsync(cnt, 0, (size_t)Gg * sizeof(int), stream);

    hipLaunchKernelGGL(k_proj_count, dim3(Nn / 256), dim3(256), 0, stream,
                       features, W, gid, proj, cnt);
    hipLaunchKernelGGL(k_scan, dim3(1), dim3(256), 0, stream,
                       cnt, offsets, cursor);
    hipLaunchKernelGGL(k_scatter_idx, dim3(Nn / 256), dim3(256), 0, stream,
                       gid, cursor, bucket);
    hipLaunchKernelGGL(k_group_mean, dim3(Gg), dim3(256), 0, stream,
                       features, bucket, offsets, cnt, out_means);
    hipLaunchKernelGGL(k_edges, dim3(Ee / 4), dim3(256), 0, stream,
                       proj, ei, out_logits);
}

// Round 3
// 273.922 us; speedup vs baseline: 7.0128x; 1.5551x over previous
//
#include <hip/hip_runtime.h>
#include <math.h>

// Problem constants (fixed by the reference setup)
constexpr int Nn = 131072;   // rows
constexpr int Dd = 256;      // feature dim
constexpr int Pp = 64;       // proj dim
constexpr int Gg = 8192;     // groups
constexpr int Ee = 260096;   // edges
constexpr float SIM_TH = 0.5f;

// ---------------------------------------------------------------------------
// K0: per-group member count (131K trivial atomics over 8192 counters).
// ---------------------------------------------------------------------------
__global__ __launch_bounds__(256) void k_count(
    const int* __restrict__ gid, int* __restrict__ cnt)
{
    const int i = blockIdx.x * 256 + threadIdx.x;
    atomicAdd(&cnt[gid[i]], 1);
}

// ---------------------------------------------------------------------------
// K1: LDS-tiled fp32 GEMM  proj[N][64] = features[N][256] @ W[256][64].
// Block: 256 threads -> tile 128 rows x 64 cols, K-slab 32.
// Thread tile: 8 rows (strided 16) x 4 cols -> acc in 32 VGPRs.
// LDS: As[128][36] (pad 36 keeps b128 alignment, spreads banks), Bs[32][64].
// Per-instr LDS access: A-reads 4 distinct banks (no conflict), B-reads
// 16 addrs x4-lane broadcast, 2-way bank alias = free.
// ---------------------------------------------------------------------------
__global__ __launch_bounds__(256) void k_proj(
    const float* __restrict__ A,          // features [N][256]
    const float* __restrict__ B,          // W [256][64]
    float* __restrict__ C)                // proj [N][64]
{
    __shared__ float As[128 * 36];        // 18 KB
    __shared__ float Bs[32 * 64];         // 8 KB

    const int tid  = threadIdx.x;
    const int row0 = blockIdx.x * 128;
    const int tr   = tid >> 4;            // 0..15
    const int tc   = tid & 15;            // 0..15 -> cols tc*4..tc*4+3

    float4 acc[8];
#pragma unroll
    for (int i = 0; i < 8; ++i) acc[i] = make_float4(0.f, 0.f, 0.f, 0.f);

    for (int k0 = 0; k0 < Dd; k0 += 32) {
        __syncthreads();
        // stage A: 128 rows x 32 ks = 1024 float4s, 4 per thread, coalesced
        // (consecutive threads -> consecutive float4s within a row slab).
#pragma unroll
        for (int q = 0; q < 4; ++q) {
            const int fidx = tid + 256 * q;          // 0..1023
            const int r = fidx >> 3;                 // 0..127
            const int j = fidx & 7;                  // 0..7 (float4 within slab)
            const float4 v = *reinterpret_cast<const float4*>(
                A + (size_t)(row0 + r) * Dd + k0 + j * 4);
            *reinterpret_cast<float4*>(&As[r * 36 + j * 4]) = v;
        }
        // stage B slab: 32 rows x 64 cols = 8 KB, contiguous in global.
#pragma unroll
        for (int q = 0; q < 2; ++q) {
            const int fidx = tid + 256 * q;          // 0..511
            const float4 v = *reinterpret_cast<const float4*>(
                B + (size_t)k0 * Pp + fidx * 4);
            *reinterpret_cast<float4*>(&Bs[fidx * 4]) = v;
        }
        __syncthreads();

#pragma unroll
        for (int kk = 0; kk < 32; kk += 4) {
            float4 b0 = *reinterpret_cast<const float4*>(&Bs[(kk + 0) * 64 + tc * 4]);
            float4 b1 = *reinterpret_cast<const float4*>(&Bs[(kk + 1) * 64 + tc * 4]);
            float4 b2 = *reinterpret_cast<const float4*>(&Bs[(kk + 2) * 64 + tc * 4]);
            float4 b3 = *reinterpret_cast<const float4*>(&Bs[(kk + 3) * 64 + tc * 4]);
#pragma unroll
            for (int i = 0; i < 8; ++i) {
                const float4 a = *reinterpret_cast<const float4*>(
                    &As[(tr + 16 * i) * 36 + kk]);
                acc[i].x = fmaf(a.x, b0.x, acc[i].x);
                acc[i].y = fmaf(a.x, b0.y, acc[i].y);
                acc[i].z = fmaf(a.x, b0.z, acc[i].z);
                acc[i].w = fmaf(a.x, b0.w, acc[i].w);
                acc[i].x = fmaf(a.y, b1.x, acc[i].x);
                acc[i].y = fmaf(a.y, b1.y, acc[i].y);
                acc[i].z = fmaf(a.y, b1.z, acc[i].z);
                acc[i].w = fmaf(a.y, b1.w, acc[i].w);
                acc[i].x = fmaf(a.z, b2.x, acc[i].x);
                acc[i].y = fmaf(a.z, b2.y, acc[i].y);
                acc[i].z = fmaf(a.z, b2.z, acc[i].z);
                acc[i].w = fmaf(a.z, b2.w, acc[i].w);
                acc[i].x = fmaf(a.w, b3.x, acc[i].x);
                acc[i].y = fmaf(a.w, b3.y, acc[i].y);
                acc[i].z = fmaf(a.w, b3.z, acc[i].z);
                acc[i].w = fmaf(a.w, b3.w, acc[i].w);
            }
        }
    }

    // epilogue: 4 x 256 B contiguous segments per wave-instr
#pragma unroll
    for (int i = 0; i < 8; ++i) {
        *reinterpret_cast<float4*>(
            C + (size_t)(row0 + tr + 16 * i) * Pp + tc * 4) = acc[i];
    }
}

// ---------------------------------------------------------------------------
// K2: single-block exclusive prefix scan over the 8192 group counts.
// ---------------------------------------------------------------------------
__global__ __launch_bounds__(256) void k_scan(
    const int* __restrict__ cnt,
    int* __restrict__ offsets,
    int* __restrict__ cursor)
{
    __shared__ int lds[256];
    const int t = threadIdx.x;
    const int base = t * 32;

    int s = 0;
#pragma unroll
    for (int j = 0; j < 32; ++j) s += cnt[base + j];
    lds[t] = s;
    __syncthreads();

    int v = s;
    for (int off = 1; off < 256; off <<= 1) {
        int add = (t >= off) ? lds[t - off] : 0;
        __syncthreads();
        v += add;
        lds[t] = v;
        __syncthreads();
    }

    int run = v - s;
    for (int j = 0; j < 32; ++j) {
        offsets[base + j] = run;
        cursor[base + j]  = run;
        run += cnt[base + j];
    }
}

// ---------------------------------------------------------------------------
// K3: scatter row indices into group buckets (counting sort, phase 2).
// ---------------------------------------------------------------------------
__global__ __launch_bounds__(256) void k_scatter_idx(
    const int* __restrict__ gid,
    int* __restrict__ cursor,
    int* __restrict__ bucket)
{
    const int i = blockIdx.x * 256 + threadIdx.x;
    const int p = atomicAdd(&cursor[gid[i]], 1);
    bucket[p] = i;
}

// ---------------------------------------------------------------------------
// K4: group means — one WAVE per group. Lane l owns cols 4l..4l+3 (float4).
// Member rows gathered as coalesced 1 KB reads; 4x unroll for independent
// loads in flight. Features are L3-resident after k_proj streamed them.
// ---------------------------------------------------------------------------
__global__ __launch_bounds__(256) void k_group_mean(
    const float* __restrict__ features,   // [N][256]
    const int* __restrict__ bucket,       // [N]
    const int* __restrict__ offsets,      // [G]
    const int* __restrict__ cnt,          // [G]
    float* __restrict__ out_means)        // [G][256]
{
    const int lane = threadIdx.x & 63;
    const int g = blockIdx.x * 4 + (threadIdx.x >> 6);
    const int n = cnt[g];
    const int start = offsets[g];
    const int col = lane * 4;

    float4 s = make_float4(0.f, 0.f, 0.f, 0.f);
    int k = 0;
    for (; k + 4 <= n; k += 4) {
        const int r0 = bucket[start + k + 0];
        const int r1 = bucket[start + k + 1];
        const int r2 = bucket[start + k + 2];
        const int r3 = bucket[start + k + 3];
        const float4 f0 = *reinterpret_cast<const float4*>(features + (size_t)r0 * Dd + col);
        const float4 f1 = *reinterpret_cast<const float4*>(features + (size_t)r1 * Dd + col);
        const float4 f2 = *reinterpret_cast<const float4*>(features + (size_t)r2 * Dd + col);
        const float4 f3 = *reinterpret_cast<const float4*>(features + (size_t)r3 * Dd + col);
        s.x += f0.x + f1.x + f2.x + f3.x;
        s.y += f0.y + f1.y + f2.y + f3.y;
        s.z += f0.z + f1.z + f2.z + f3.z;
        s.w += f0.w + f1.w + f2.w + f3.w;
    }
    for (; k < n; ++k) {
        const int r = bucket[start + k];
        const float4 f = *reinterpret_cast<const float4*>(features + (size_t)r * Dd + col);
        s.x += f.x; s.y += f.y; s.z += f.z; s.w += f.w;
    }
    const float inv = 1.0f / (float)max(n, 1);
    s.x *= inv; s.y *= inv; s.z *= inv; s.w *= inv;
    *reinterpret_cast<float4*>(out_means + (size_t)g * Dd + col) = s;
}

// ---------------------------------------------------------------------------
// K5: edges — 16 lanes per edge, float4 per lane (one 256 B row per quarter
// wave), dot4 in-register, 4-step shuffle reduce, sigmoid.
// ---------------------------------------------------------------------------
__global__ __launch_bounds__(256) void k_edges(
    const float* __restrict__ proj,       // [N][64]
    const int*   __restrict__ ei,         // [2][E]
    float* __restrict__ out_logits)       // [E]
{
    const int tid = threadIdx.x;
    const int e = blockIdx.x * 16 + (tid >> 4);
    const int sub = tid & 15;
    const int s = ei[e];
    const int t = ei[Ee + e];
    const float4 ps = *reinterpret_cast<const float4*>(proj + (size_t)s * Pp + sub * 4);
    const float4 pt = *reinterpret_cast<const float4*>(proj + (size_t)t * Pp + sub * 4);
    float v = ps.x * pt.x + ps.y * pt.y + ps.z * pt.z + ps.w * pt.w;
#pragma unroll
    for (int off = 8; off >= 1; off >>= 1)
        v += __shfl_xor(v, off, 64);
    if (sub == 0)
        out_logits[e] = 1.0f / (1.0f + __expf(-(v - SIM_TH)));
}

// ---------------------------------------------------------------------------
extern "C" void kernel_launch(void* const* d_in, const int* in_sizes, int n_in,
                              void* d_out, int out_size, void* d_ws, size_t ws_size,
                              hipStream_t stream)
{
    const float* features = (const float*)d_in[0];
    const float* W        = (const float*)d_in[1];
    const int*   ei       = (const int*)d_in[2];
    const int*   gid      = (const int*)d_in[3];
    // d_in[4] = num_groups scalar (fixed at 8192, hardcoded)

    float* out_means  = (float*)d_out;                    // [G*D]
    float* out_logits = out_means + (size_t)Gg * Dd;      // [E]

    float* proj    = (float*)d_ws;                        // N*P floats (32 MB)
    int*   bucket  = (int*)(proj + (size_t)Nn * Pp);      // [N]
    int*   cnt     = bucket + Nn;                         // [G]
    int*   offsets = cnt + Gg;                            // [G]
    int*   cursor  = offsets + Gg;                        // [G]

    hipMemsetAsync(cnt, 0, (size_t)Gg * sizeof(int), stream);

    hipLaunchKernelGGL(k_count, dim3(Nn / 256), dim3(256), 0, stream, gid, cnt);
    hipLaunchKernelGGL(k_proj, dim3(Nn / 128), dim3(256), 0, stream,
                       features, W, proj);
    hipLaunchKernelGGL(k_scan, dim3(1), dim3(256), 0, stream,
                       cnt, offsets, cursor);
    hipLaunchKernelGGL(k_scatter_idx, dim3(Nn / 256), dim3(256), 0, stream,
                       gid, cursor, bucket);
    hipLaunchKernelGGL(k_group_mean, dim3(Gg / 4), dim3(256), 0, stream,
                       features, bucket, offsets, cnt, out_means);
    hipLaunchKernelGGL(k_edges, dim3(Ee / 16), dim3(256), 0, stream,
                       proj, ei, out_logits);
}

// Round 4
// 269.971 us; speedup vs baseline: 7.1154x; 1.0146x over previous
//
#include <hip/hip_runtime.h>
#include <math.h>

// Problem constants (fixed by the reference setup)
constexpr int Nn = 131072;   // rows
constexpr int Dd = 256;      // feature dim
constexpr int Pp = 64;       // proj dim
constexpr int Gg = 8192;     // groups
constexpr int Ee = 260096;   // edges
constexpr float SIM_TH = 0.5f;

typedef _Float16 half8 __attribute__((ext_vector_type(8)));
typedef float floatx4 __attribute__((ext_vector_type(4)));

// ---------------------------------------------------------------------------
// K_wfrag: pre-swizzle W [256][64] fp32 into MFMA B-fragment order, fp16.
// Frag (c,t): k-chunk c in 0..7 (K=32 each), n-tile t in 0..3 (16 cols).
// Lane l, elem j holds B[k = c*32 + (l>>4)*8 + j][n = t*16 + (l&15)].
// Flat: Wf[((c*4 + t)*64 + l)*8 + j].  16384 f16 = 32 KB, L2-resident.
// ---------------------------------------------------------------------------
__global__ __launch_bounds__(256) void k_wfrag(
    const float* __restrict__ W, _Float16* __restrict__ Wf)
{
    const int f = blockIdx.x * 256 + threadIdx.x;   // 0..16383
    const int j = f & 7;
    const int l = (f >> 3) & 63;
    const int t = (f >> 9) & 3;
    const int c = f >> 11;
    const int k = c * 32 + (l >> 4) * 8 + j;
    const int n = t * 16 + (l & 15);
    Wf[f] = (_Float16)W[k * Pp + n];
}

// ---------------------------------------------------------------------------
// K0: per-group member count (131K trivial atomics over 8192 counters).
// ---------------------------------------------------------------------------
__global__ __launch_bounds__(256) void k_count(
    const int* __restrict__ gid, int* __restrict__ cnt)
{
    const int i = blockIdx.x * 256 + threadIdx.x;
    atomicAdd(&cnt[gid[i]], 1);
}

// ---------------------------------------------------------------------------
// K1: fp16 MFMA projection, LDS-free & barrier-free.
// Wave w computes rows [blk*64 + w*16, +16) x all 64 cols: 4 n-tiles,
// K swept in 8 chunks of 32 via v_mfma_f32_16x16x32_f16.
// A-frag loaded straight from global (2 float4/lane/chunk, 16 rows x 128 B
// coalesced segments), cvt to fp16 inline. B-frags: single b128 coalesced
// loads from the pre-swizzled 32 KB Wf (L2-resident, read by all blocks).
// ---------------------------------------------------------------------------
__global__ __launch_bounds__(256) void k_proj(
    const float* __restrict__ A,          // features [N][256]
    const _Float16* __restrict__ Wf,      // swizzled B-frags
    float* __restrict__ C)                // proj [N][64]
{
    const int l = threadIdx.x & 63;
    const int w = threadIdx.x >> 6;
    const int rowbase = blockIdx.x * 64 + w * 16;
    const int am = l & 15;                // A-frag row within tile
    const int q  = l >> 4;                // quad 0..3

    const float* __restrict__ arow = A + (size_t)(rowbase + am) * Dd + q * 8;
    const half8* __restrict__ bfrag = reinterpret_cast<const half8*>(Wf) + l;

    floatx4 acc[4];
#pragma unroll
    for (int t = 0; t < 4; ++t) acc[t] = (floatx4){0.f, 0.f, 0.f, 0.f};

#pragma unroll
    for (int c = 0; c < 8; ++c) {
        const float4 fa = *reinterpret_cast<const float4*>(arow + c * 32);
        const float4 fb = *reinterpret_cast<const float4*>(arow + c * 32 + 4);
        half8 a;
        a[0] = (_Float16)fa.x; a[1] = (_Float16)fa.y;
        a[2] = (_Float16)fa.z; a[3] = (_Float16)fa.w;
        a[4] = (_Float16)fb.x; a[5] = (_Float16)fb.y;
        a[6] = (_Float16)fb.z; a[7] = (_Float16)fb.w;
        const half8 b0 = bfrag[(c * 4 + 0) * 64];
        const half8 b1 = bfrag[(c * 4 + 1) * 64];
        const half8 b2 = bfrag[(c * 4 + 2) * 64];
        const half8 b3 = bfrag[(c * 4 + 3) * 64];
        acc[0] = __builtin_amdgcn_mfma_f32_16x16x32_f16(a, b0, acc[0], 0, 0, 0);
        acc[1] = __builtin_amdgcn_mfma_f32_16x16x32_f16(a, b1, acc[1], 0, 0, 0);
        acc[2] = __builtin_amdgcn_mfma_f32_16x16x32_f16(a, b2, acc[2], 0, 0, 0);
        acc[3] = __builtin_amdgcn_mfma_f32_16x16x32_f16(a, b3, acc[3], 0, 0, 0);
    }

    // C/D layout: col = l&15, row = q*4 + reg  (m89-verified mapping)
#pragma unroll
    for (int t = 0; t < 4; ++t) {
#pragma unroll
        for (int r = 0; r < 4; ++r) {
            C[(size_t)(rowbase + q * 4 + r) * Pp + t * 16 + (l & 15)] = acc[t][r];
        }
    }
}

// ---------------------------------------------------------------------------
// K2: single-block exclusive prefix scan over the 8192 group counts.
// ---------------------------------------------------------------------------
__global__ __launch_bounds__(256) void k_scan(
    const int* __restrict__ cnt,
    int* __restrict__ offsets,
    int* __restrict__ cursor)
{
    __shared__ int lds[256];
    const int t = threadIdx.x;
    const int base = t * 32;

    int s = 0;
#pragma unroll
    for (int j = 0; j < 32; ++j) s += cnt[base + j];
    lds[t] = s;
    __syncthreads();

    int v = s;
    for (int off = 1; off < 256; off <<= 1) {
        int add = (t >= off) ? lds[t - off] : 0;
        __syncthreads();
        v += add;
        lds[t] = v;
        __syncthreads();
    }

    int run = v - s;
    for (int j = 0; j < 32; ++j) {
        offsets[base + j] = run;
        cursor[base + j]  = run;
        run += cnt[base + j];
    }
}

// ---------------------------------------------------------------------------
// K3: scatter row indices into group buckets (counting sort, phase 2).
// ---------------------------------------------------------------------------
__global__ __launch_bounds__(256) void k_scatter_idx(
    const int* __restrict__ gid,
    int* __restrict__ cursor,
    int* __restrict__ bucket)
{
    const int i = blockIdx.x * 256 + threadIdx.x;
    const int p = atomicAdd(&cursor[gid[i]], 1);
    bucket[p] = i;
}

// ---------------------------------------------------------------------------
// K4: group means — one wave per group, lane = float4 column slice.
// 8-deep unrolled independent gathers (coalesced 1 KB rows, L3-warm).
// ---------------------------------------------------------------------------
__global__ __launch_bounds__(256) void k_group_mean(
    const float* __restrict__ features,   // [N][256]
    const int* __restrict__ bucket,       // [N]
    const int* __restrict__ offsets,      // [G]
    const int* __restrict__ cnt,          // [G]
    float* __restrict__ out_means)        // [G][256]
{
    const int lane = threadIdx.x & 63;
    const int g = blockIdx.x * 4 + (threadIdx.x >> 6);
    const int n = cnt[g];
    const int start = offsets[g];
    const int col = lane * 4;

    float4 s = make_float4(0.f, 0.f, 0.f, 0.f);
    int k = 0;
    for (; k + 8 <= n; k += 8) {
        int r[8];
#pragma unroll
        for (int u = 0; u < 8; ++u) r[u] = bucket[start + k + u];
        float4 f[8];
#pragma unroll
        for (int u = 0; u < 8; ++u)
            f[u] = *reinterpret_cast<const float4*>(features + (size_t)r[u] * Dd + col);
#pragma unroll
        for (int u = 0; u < 8; ++u) {
            s.x += f[u].x; s.y += f[u].y; s.z += f[u].z; s.w += f[u].w;
        }
    }
    for (; k < n; ++k) {
        const int r = bucket[start + k];
        const float4 f = *reinterpret_cast<const float4*>(features + (size_t)r * Dd + col);
        s.x += f.x; s.y += f.y; s.z += f.z; s.w += f.w;
    }
    const float inv = 1.0f / (float)max(n, 1);
    s.x *= inv; s.y *= inv; s.z *= inv; s.w *= inv;
    *reinterpret_cast<float4*>(out_means + (size_t)g * Dd + col) = s;
}

// ---------------------------------------------------------------------------
// K5: edges — 4 edges per 16-lane subgroup: 8 independent 256 B row gathers
// in flight, 4 dot4s, shared shuffle reduction, 4 semi-coalesced stores.
// ---------------------------------------------------------------------------
__global__ __launch_bounds__(256) void k_edges(
    const float* __restrict__ proj,       // [N][64]
    const int*   __restrict__ ei,         // [2][E]
    float* __restrict__ out_logits)       // [E]
{
    const int sub = threadIdx.x & 15;
    const int sg  = blockIdx.x * 16 + (threadIdx.x >> 4);
    const int e0  = sg * 4;

    const int s0 = ei[e0 + 0], s1 = ei[e0 + 1], s2 = ei[e0 + 2], s3 = ei[e0 + 3];
    const int t0 = ei[Ee + e0 + 0], t1 = ei[Ee + e0 + 1];
    const int t2 = ei[Ee + e0 + 2], t3 = ei[Ee + e0 + 3];

    const int co = sub * 4;
    const float4 a0 = *reinterpret_cast<const float4*>(proj + (size_t)s0 * Pp + co);
    const float4 a1 = *reinterpret_cast<const float4*>(proj + (size_t)s1 * Pp + co);
    const float4 a2 = *reinterpret_cast<const float4*>(proj + (size_t)s2 * Pp + co);
    const float4 a3 = *reinterpret_cast<const float4*>(proj + (size_t)s3 * Pp + co);
    const float4 b0 = *reinterpret_cast<const float4*>(proj + (size_t)t0 * Pp + co);
    const float4 b1 = *reinterpret_cast<const float4*>(proj + (size_t)t1 * Pp + co);
    const float4 b2 = *reinterpret_cast<const float4*>(proj + (size_t)t2 * Pp + co);
    const float4 b3 = *reinterpret_cast<const float4*>(proj + (size_t)t3 * Pp + co);

    float v0 = a0.x * b0.x + a0.y * b0.y + a0.z * b0.z + a0.w * b0.w;
    float v1 = a1.x * b1.x + a1.y * b1.y + a1.z * b1.z + a1.w * b1.w;
    float v2 = a2.x * b2.x + a2.y * b2.y + a2.z * b2.z + a2.w * b2.w;
    float v3 = a3.x * b3.x + a3.y * b3.y + a3.z * b3.z + a3.w * b3.w;

#pragma unroll
    for (int off = 8; off >= 1; off >>= 1) {
        v0 += __shfl_xor(v0, off, 64);
        v1 += __shfl_xor(v1, off, 64);
        v2 += __shfl_xor(v2, off, 64);
        v3 += __shfl_xor(v3, off, 64);
    }

    if (sub < 4) {
        const float v = (sub == 0) ? v0 : (sub == 1) ? v1 : (sub == 2) ? v2 : v3;
        out_logits[e0 + sub] = 1.0f / (1.0f + __expf(-(v - SIM_TH)));
    }
}

// ---------------------------------------------------------------------------
extern "C" void kernel_launch(void* const* d_in, const int* in_sizes, int n_in,
                              void* d_out, int out_size, void* d_ws, size_t ws_size,
                              hipStream_t stream)
{
    const float* features = (const float*)d_in[0];
    const float* W        = (const float*)d_in[1];
    const int*   ei       = (const int*)d_in[2];
    const int*   gid      = (const int*)d_in[3];
    // d_in[4] = num_groups scalar (fixed at 8192, hardcoded)

    float* out_means  = (float*)d_out;                    // [G*D]
    float* out_logits = out_means + (size_t)Gg * Dd;      // [E]

    float*     proj    = (float*)d_ws;                    // N*P floats (32 MB)
    int*       bucket  = (int*)(proj + (size_t)Nn * Pp);  // [N]
    int*       cnt     = bucket + Nn;                     // [G]
    int*       offsets = cnt + Gg;                        // [G]
    int*       cursor  = offsets + Gg;                    // [G]
    _Float16*  Wf      = (_Float16*)(cursor + Gg);        // 16384 f16 (32 KB)

    hipMemsetAsync(cnt, 0, (size_t)Gg * sizeof(int), stream);

    hipLaunchKernelGGL(k_wfrag, dim3(16384 / 256), dim3(256), 0, stream, W, Wf);
    hipLaunchKernelGGL(k_count, dim3(Nn / 256), dim3(256), 0, stream, gid, cnt);
    hipLaunchKernelGGL(k_proj, dim3(Nn / 64), dim3(256), 0, stream,
                       features, Wf, proj);
    hipLaunchKernelGGL(k_scan, dim3(1), dim3(256), 0, stream,
                       cnt, offsets, cursor);
    hipLaunchKernelGGL(k_scatter_idx, dim3(Nn / 256), dim3(256), 0, stream,
                       gid, cursor, bucket);
    hipLaunchKernelGGL(k_group_mean, dim3(Gg / 4), dim3(256), 0, stream,
                       features, bucket, offsets, cnt, out_means);
    hipLaunchKernelGGL(k_edges, dim3(Ee / 64), dim3(256), 0, stream,
                       proj, ei, out_logits);
}

// Round 5
// 256.804 us; speedup vs baseline: 7.4802x; 1.0513x over previous
//
#include <hip/hip_runtime.h>
#include <math.h>

// Problem constants (fixed by the reference setup)
constexpr int Nn = 131072;   // rows
constexpr int Dd = 256;      // feature dim
constexpr int Pp = 64;       // proj dim
constexpr int Gg = 8192;     // groups
constexpr int Ee = 260096;   // edges
constexpr float SIM_TH = 0.5f;

typedef _Float16 half8 __attribute__((ext_vector_type(8)));
typedef float floatx4 __attribute__((ext_vector_type(4)));

// ---------------------------------------------------------------------------
// K0: per-group member count (131K atomics over 8192 counters) + W swizzle.
// The first 16384 threads additionally pre-swizzle W [256][64] fp32 into
// MFMA B-fragment order fp16: lane l, elem j of frag (c,t) holds
// B[k = c*32 + (l>>4)*8 + j][n = t*16 + (l&15)];  flat Wf[((c*4+t)*64+l)*8+j].
// ---------------------------------------------------------------------------
__global__ __launch_bounds__(256) void k_count_wfrag(
    const int* __restrict__ gid, int* __restrict__ cnt,
    const float* __restrict__ W, _Float16* __restrict__ Wf)
{
    const int i = blockIdx.x * 256 + threadIdx.x;
    atomicAdd(&cnt[gid[i]], 1);
    if (i < 16384) {
        const int j = i & 7;
        const int l = (i >> 3) & 63;
        const int t = (i >> 9) & 3;
        const int c = i >> 11;
        const int k = c * 32 + (l >> 4) * 8 + j;
        const int n = t * 16 + (l & 15);
        Wf[i] = (_Float16)W[k * Pp + n];
    }
}

// ---------------------------------------------------------------------------
// K1: fp16 MFMA projection, LDS-free & barrier-free. proj stored as fp16.
// Wave w: rows [blk*64 + w*16, +16) x all 64 cols; K in 8 chunks of 32 via
// v_mfma_f32_16x16x32_f16. A-frags straight from global (cvt inline);
// B-frags single coalesced b128 loads from 32 KB L2-resident Wf.
// ---------------------------------------------------------------------------
__global__ __launch_bounds__(256) void k_proj(
    const float* __restrict__ A,          // features [N][256]
    const _Float16* __restrict__ Wf,      // swizzled B-frags
    _Float16* __restrict__ C)             // proj [N][64] fp16
{
    const int l = threadIdx.x & 63;
    const int w = threadIdx.x >> 6;
    const int rowbase = blockIdx.x * 64 + w * 16;
    const int am = l & 15;                // A-frag row within tile
    const int q  = l >> 4;                // quad 0..3

    const float* __restrict__ arow = A + (size_t)(rowbase + am) * Dd + q * 8;
    const half8* __restrict__ bfrag = reinterpret_cast<const half8*>(Wf) + l;

    floatx4 acc[4];
#pragma unroll
    for (int t = 0; t < 4; ++t) acc[t] = (floatx4){0.f, 0.f, 0.f, 0.f};

#pragma unroll
    for (int c = 0; c < 8; ++c) {
        const float4 fa = *reinterpret_cast<const float4*>(arow + c * 32);
        const float4 fb = *reinterpret_cast<const float4*>(arow + c * 32 + 4);
        half8 a;
        a[0] = (_Float16)fa.x; a[1] = (_Float16)fa.y;
        a[2] = (_Float16)fa.z; a[3] = (_Float16)fa.w;
        a[4] = (_Float16)fb.x; a[5] = (_Float16)fb.y;
        a[6] = (_Float16)fb.z; a[7] = (_Float16)fb.w;
        const half8 b0 = bfrag[(c * 4 + 0) * 64];
        const half8 b1 = bfrag[(c * 4 + 1) * 64];
        const half8 b2 = bfrag[(c * 4 + 2) * 64];
        const half8 b3 = bfrag[(c * 4 + 3) * 64];
        acc[0] = __builtin_amdgcn_mfma_f32_16x16x32_f16(a, b0, acc[0], 0, 0, 0);
        acc[1] = __builtin_amdgcn_mfma_f32_16x16x32_f16(a, b1, acc[1], 0, 0, 0);
        acc[2] = __builtin_amdgcn_mfma_f32_16x16x32_f16(a, b2, acc[2], 0, 0, 0);
        acc[3] = __builtin_amdgcn_mfma_f32_16x16x32_f16(a, b3, acc[3], 0, 0, 0);
    }

    // C/D layout: col = l&15, row = q*4 + reg  (m89-verified mapping)
#pragma unroll
    for (int t = 0; t < 4; ++t) {
#pragma unroll
        for (int r = 0; r < 4; ++r) {
            C[(size_t)(rowbase + q * 4 + r) * Pp + t * 16 + (l & 15)] =
                (_Float16)acc[t][r];
        }
    }
}

// ---------------------------------------------------------------------------
// K2: single-block exclusive prefix scan over the 8192 group counts.
// ---------------------------------------------------------------------------
__global__ __launch_bounds__(256) void k_scan(
    const int* __restrict__ cnt,
    int* __restrict__ offsets,
    int* __restrict__ cursor)
{
    __shared__ int lds[256];
    const int t = threadIdx.x;
    const int base = t * 32;

    int s = 0;
#pragma unroll
    for (int j = 0; j < 32; ++j) s += cnt[base + j];
    lds[t] = s;
    __syncthreads();

    int v = s;
    for (int off = 1; off < 256; off <<= 1) {
        int add = (t >= off) ? lds[t - off] : 0;
        __syncthreads();
        v += add;
        lds[t] = v;
        __syncthreads();
    }

    int run = v - s;
    for (int j = 0; j < 32; ++j) {
        offsets[base + j] = run;
        cursor[base + j]  = run;
        run += cnt[base + j];
    }
}

// ---------------------------------------------------------------------------
// K3: scatter row indices into group buckets (counting sort, phase 2).
// ---------------------------------------------------------------------------
__global__ __launch_bounds__(256) void k_scatter_idx(
    const int* __restrict__ gid,
    int* __restrict__ cursor,
    int* __restrict__ bucket)
{
    const int i = blockIdx.x * 256 + threadIdx.x;
    const int p = atomicAdd(&cursor[gid[i]], 1);
    bucket[p] = i;
}

// ---------------------------------------------------------------------------
// K4: group means — one wave per group, lane = float4 column slice.
// 8-deep unrolled independent gathers (coalesced 1 KB rows, L3-warm).
// ---------------------------------------------------------------------------
__global__ __launch_bounds__(256) void k_group_mean(
    const float* __restrict__ features,   // [N][256]
    const int* __restrict__ bucket,       // [N]
    const int* __restrict__ offsets,      // [G]
    const int* __restrict__ cnt,          // [G]
    float* __restrict__ out_means)        // [G][256]
{
    const int lane = threadIdx.x & 63;
    const int g = blockIdx.x * 4 + (threadIdx.x >> 6);
    const int n = cnt[g];
    const int start = offsets[g];
    const int col = lane * 4;

    float4 s = make_float4(0.f, 0.f, 0.f, 0.f);
    int k = 0;
    for (; k + 8 <= n; k += 8) {
        int r[8];
#pragma unroll
        for (int u = 0; u < 8; ++u) r[u] = bucket[start + k + u];
        float4 f[8];
#pragma unroll
        for (int u = 0; u < 8; ++u)
            f[u] = *reinterpret_cast<const float4*>(features + (size_t)r[u] * Dd + col);
#pragma unroll
        for (int u = 0; u < 8; ++u) {
            s.x += f[u].x; s.y += f[u].y; s.z += f[u].z; s.w += f[u].w;
        }
    }
    for (; k < n; ++k) {
        const int r = bucket[start + k];
        const float4 f = *reinterpret_cast<const float4*>(features + (size_t)r * Dd + col);
        s.x += f.x; s.y += f.y; s.z += f.z; s.w += f.w;
    }
    const float inv = 1.0f / (float)max(n, 1);
    s.x *= inv; s.y *= inv; s.z *= inv; s.w *= inv;
    *reinterpret_cast<float4*>(out_means + (size_t)g * Dd + col) = s;
}

// ---------------------------------------------------------------------------
// K5: edges over fp16 proj — 8 lanes per edge (half8 = 8 cols each),
// 4 edges per subgroup -> 8 independent 16 B loads in flight per lane,
// 3-step shuffle reduce, sigmoid. proj footprint 16 MB (L2/L3-resident).
// ---------------------------------------------------------------------------
__global__ __launch_bounds__(256) void k_edges(
    const _Float16* __restrict__ proj,    // [N][64] fp16
    const int*      __restrict__ ei,      // [2][E]
    float* __restrict__ out_logits)       // [E]
{
    const int sub = threadIdx.x & 7;                       // lane within edge
    const int sg  = blockIdx.x * 32 + (threadIdx.x >> 3);  // subgroup id
    const int e0  = sg * 4;

    int s[4], t[4];
#pragma unroll
    for (int u = 0; u < 4; ++u) { s[u] = ei[e0 + u]; t[u] = ei[Ee + e0 + u]; }

    half8 a[4], b[4];
#pragma unroll
    for (int u = 0; u < 4; ++u) {
        a[u] = *reinterpret_cast<const half8*>(proj + (size_t)s[u] * Pp + sub * 8);
        b[u] = *reinterpret_cast<const half8*>(proj + (size_t)t[u] * Pp + sub * 8);
    }

    float v[4];
#pragma unroll
    for (int u = 0; u < 4; ++u) {
        float acc = 0.f;
#pragma unroll
        for (int j = 0; j < 8; ++j)
            acc = fmaf((float)a[u][j], (float)b[u][j], acc);
        v[u] = acc;
    }

#pragma unroll
    for (int off = 4; off >= 1; off >>= 1) {
#pragma unroll
        for (int u = 0; u < 4; ++u) v[u] += __shfl_xor(v[u], off, 64);
    }

    if (sub < 4) {
        const float x = v[sub];
        out_logits[e0 + sub] = 1.0f / (1.0f + __expf(-(x - SIM_TH)));
    }
}

// ---------------------------------------------------------------------------
extern "C" void kernel_launch(void* const* d_in, const int* in_sizes, int n_in,
                              void* d_out, int out_size, void* d_ws, size_t ws_size,
                              hipStream_t stream)
{
    const float* features = (const float*)d_in[0];
    const float* W        = (const float*)d_in[1];
    const int*   ei       = (const int*)d_in[2];
    const int*   gid      = (const int*)d_in[3];
    // d_in[4] = num_groups scalar (fixed at 8192, hardcoded)

    float* out_means  = (float*)d_out;                    // [G*D]
    float* out_logits = out_means + (size_t)Gg * Dd;      // [E]

    _Float16*  proj    = (_Float16*)d_ws;                 // N*P f16 (16 MB)
    int*       bucket  = (int*)(proj + (size_t)Nn * Pp);  // [N]
    int*       cnt     = bucket + Nn;                     // [G]
    int*       offsets = cnt + Gg;                        // [G]
    int*       cursor  = offsets + Gg;                    // [G]
    _Float16*  Wf      = (_Float16*)(cursor + Gg);        // 16384 f16 (32 KB)

    hipMemsetAsync(cnt, 0, (size_t)Gg * sizeof(int), stream);

    hipLaunchKernelGGL(k_count_wfrag, dim3(Nn / 256), dim3(256), 0, stream,
                       gid, cnt, W, Wf);
    hipLaunchKernelGGL(k_proj, dim3(Nn / 64), dim3(256), 0, stream,
                       features, Wf, proj);
    hipLaunchKernelGGL(k_scan, dim3(1), dim3(256), 0, stream,
                       cnt, offsets, cursor);
    hipLaunchKernelGGL(k_scatter_idx, dim3(Nn / 256), dim3(256), 0, stream,
                       gid, cursor, bucket);
    hipLaunchKernelGGL(k_group_mean, dim3(Gg / 4), dim3(256), 0, stream,
                       features, bucket, offsets, cnt, out_means);
    hipLaunchKernelGGL(k_edges, dim3(Ee / 128), dim3(256), 0, stream,
                       proj, ei, out_logits);
}